// Round 5
// baseline (3051.903 us; speedup 1.0000x reference)
//
#include <hip/hip_runtime.h>
#include <stdint.h>

#define BB 8
#define NN 4096
#define MM 1024
#define KK 32

__device__ __forceinline__ float bf2f(unsigned short u) {
    union { unsigned int i; float f; } v; v.i = ((unsigned int)u) << 16; return v.f;
}
__device__ __forceinline__ unsigned short f2bf(float f) {
    union { float f; unsigned int i; } v; v.f = f;
    unsigned int x = v.i;
    x += 0x7fffu + ((x >> 16) & 1u);
    return (unsigned short)(x >> 16);
}
__device__ __forceinline__ float swishf(float y) {
    return __fdividef(y, 1.0f + __expf(-y));
}

// out element offsets (dtype-independent)
#define OUT0_OFF 0
#define OUT1_OFF 1048576
#define OUT2_OFF 1073152

// ---------------- dtype probe: even-index ushorts of features.
__global__ void k_detect(const unsigned short* __restrict__ f, int* __restrict__ flag) {
    int lane = threadIdx.x;
    unsigned short u = f[lane * 2];
    float x = fabsf(bf2f(u));
    bool ext = (u != 0) && (x > 100.0f || x < 1e-30f);
    unsigned long long m = __ballot(ext);
    if (lane == 0) *flag = (__popcll(m) >= 16) ? 1 : 0;
}

// ---------------- generic convert (coords)
__global__ __launch_bounds__(256) void k_cvt(
    const void* __restrict__ src, float* __restrict__ dst,
    const int* __restrict__ flag, int n)
{
    int idx = blockIdx.x * 256 + threadIdx.x;
    if (idx >= n) return;
    dst[idx] = (*flag) ? ((const float*)src)[idx]
                       : bf2f(((const unsigned short*)src)[idx]);
}

// ---------------- params convert into one canonical f32 buffer
__global__ __launch_bounds__(256) void k_cvt_params(
    const void* W1, const void* b1, const void* g1, const void* be1,
    const void* W2, const void* b2, const void* g2, const void* be2,
    float* __restrict__ dst, const int* __restrict__ flag)
{
    int idx = blockIdx.x * 256 + threadIdx.x;
    if (idx >= 13056) return;
    const void* src; int off;
    if (idx < 4288)       { src = W1;  off = idx; }
    else if (idx < 4352)  { src = b1;  off = idx - 4288; }
    else if (idx < 4416)  { src = g1;  off = idx - 4352; }
    else if (idx < 4480)  { src = be1; off = idx - 4416; }
    else if (idx < 12672) { src = W2;  off = idx - 4480; }
    else if (idx < 12800) { src = b2;  off = idx - 12672; }
    else if (idx < 12928) { src = g2;  off = idx - 12800; }
    else                  { src = be2; off = idx - 12928; }
    dst[idx] = (*flag) ? ((const float*)src)[off]
                       : bf2f(((const unsigned short*)src)[off]);
}

// ---------------- FPS in f64 (mirrors np float64 golden): 1 block per batch
__global__ __launch_bounds__(1024) void k_fps(
    const float* __restrict__ coordsC,  // [B][3][N] (f32, exact bf16)
    float* __restrict__ centersF,       // [B][M][4] x,y,z,0
    void* __restrict__ d_out, const int* __restrict__ flag)
{
    __shared__ int hist[MM];
    __shared__ double pb[2][16];
    __shared__ int pi[2][16];
    int b = blockIdx.x;
    int t = threadIdx.x;
    const float* cb = coordsC + (size_t)b * 3 * NN;
    double px[4], py[4], pz[4], dist[4];
    double x0 = (double)cb[0], y0 = (double)cb[NN], z0 = (double)cb[2 * NN];
#pragma unroll
    for (int i = 0; i < 4; i++) {
        int p = t + i * 1024;
        px[i] = (double)cb[p]; py[i] = (double)cb[NN + p]; pz[i] = (double)cb[2 * NN + p];
        double dx = px[i] - x0, dy = py[i] - y0, dz = pz[i] - z0;
        dist[i] = (dx * dx + dy * dy) + dz * dz;
    }
    if (t == 0) hist[0] = 0;
    int lane = t & 63, wid = t >> 6;
#pragma unroll 1
    for (int s = 1; s < MM; s++) {
        double bd = dist[0]; int bp = t;
#pragma unroll
        for (int i = 1; i < 4; i++) {
            int p = t + i * 1024;
            bool rep = dist[i] > bd;   // strict: ties keep lower index
            bd = rep ? dist[i] : bd; bp = rep ? p : bp;
        }
#pragma unroll
        for (int m = 32; m >= 1; m >>= 1) {
            double od = __shfl_xor(bd, m, 64);
            int op = __shfl_xor(bp, m, 64);
            bool rep = (od > bd) || (od == bd && op < bp);
            bd = rep ? od : bd; bp = rep ? op : bp;
        }
        int par = s & 1;
        if (lane == 0) { pb[par][wid] = bd; pi[par][wid] = bp; }
        __syncthreads();
        double wd = pb[par][0]; int wp = pi[par][0];
#pragma unroll
        for (int w = 1; w < 16; w++) {
            double od = pb[par][w]; int op = pi[par][w];
            bool rep = (od > wd) || (od == wd && op < wp);
            wd = rep ? od : wd; wp = rep ? op : wp;
        }
        if (t == 0) hist[s] = wp;
        double fx = (double)cb[wp], fy = (double)cb[NN + wp], fz = (double)cb[2 * NN + wp];
#pragma unroll
        for (int i = 0; i < 4; i++) {
            double dx = px[i] - fx, dy = py[i] - fy, dz = pz[i] - fz;
            double d = (dx * dx + dy * dy) + dz * dz;
            dist[i] = fmin(dist[i], d);
        }
    }
    __syncthreads();
    int far = hist[t];
    float X = cb[far], Y = cb[NN + far], Z = cb[2 * NN + far];
    int fl = *flag;
    size_t o1 = OUT1_OFF;
    if (fl) {
        float* o = (float*)d_out;
        o[o1 + (size_t)(b * 3 + 0) * MM + t] = X;
        o[o1 + (size_t)(b * 3 + 1) * MM + t] = Y;
        o[o1 + (size_t)(b * 3 + 2) * MM + t] = Z;
    } else {
        unsigned short* o = (unsigned short*)d_out;
        o[o1 + (size_t)(b * 3 + 0) * MM + t] = f2bf(X);
        o[o1 + (size_t)(b * 3 + 1) * MM + t] = f2bf(Y);
        o[o1 + (size_t)(b * 3 + 2) * MM + t] = f2bf(Z);
    }
    *(float4*)(centersF + ((size_t)b * MM + t) * 4) = make_float4(X, Y, Z, 0.f);
}

// ---------------- kNN in f64 (mirrors np float64 golden expansion):
// d = (cc + pp) - 2*dot, K=32 smallest by (d, idx) lex. 1 wave per center.
#define RESCAN(G) { \
    double gd = 1.0e300; int ga = (G) * 8; \
    _Pragma("unroll") \
    for (int i = 0; i < 8; i++) { \
        int sl = (G) * 8 + i; \
        unsigned int bit = (sl < 32) ? (elo >> sl) : (ehi >> (sl - 32)); \
        double cd = (bit & 1u) ? 1.0e300 : d[sl]; \
        bool rep = cd < gd; \
        gd = rep ? cd : gd; ga = rep ? sl : ga; \
    } \
    g8[(G)] = gd; a8[(G)] = ga; }

__global__ __launch_bounds__(64, 1) void k_knn(
    const float* __restrict__ coordsC,
    const float* __restrict__ centersF,
    int* __restrict__ nidx)
{
    int bm = blockIdx.x;
    int b = bm >> 10;
    int lane = threadIdx.x;
    const float* cb = coordsC + (size_t)b * 3 * NN;
    float4 ctr = *(const float4*)(centersF + (size_t)bm * 4);
    double cx = (double)ctr.x, cy = (double)ctr.y, cz = (double)ctr.z;
    double cc = (cx * cx + cy * cy) + cz * cz;
    double d[64];
#pragma unroll 4
    for (int j = 0; j < 64; j++) {
        int p = j * 64 + lane;
        double x = (double)cb[p], y = (double)cb[NN + p], z = (double)cb[2 * NN + p];
        double pp = (x * x + y * y) + z * z;
        double dt = (cx * x + cy * y) + cz * z;
        d[j] = (cc + pp) - 2.0 * dt;
    }
    double g8[8]; int a8[8];
#pragma unroll
    for (int g = 0; g < 8; g++) {
        double gd = d[g * 8]; int ga = g * 8;
#pragma unroll
        for (int i = 1; i < 8; i++) {
            int sl = g * 8 + i;
            bool rep = d[sl] < gd;
            gd = rep ? d[sl] : gd; ga = rep ? sl : ga;
        }
        g8[g] = gd; a8[g] = ga;
    }
    unsigned int elo = 0, ehi = 0;
    int res = 0;
#pragma unroll 1
    for (int it = 0; it < 32; it++) {
        double bd = g8[0]; int ba = a8[0];
#pragma unroll
        for (int g = 1; g < 8; g++) {
            bool rep = g8[g] < bd;
            bd = rep ? g8[g] : bd; ba = rep ? a8[g] : ba;
        }
        int bp = ba * 64 + lane;
        double wd = bd; int wp = bp;
#pragma unroll
        for (int s = 32; s >= 1; s >>= 1) {
            double od = __shfl_xor(wd, s, 64);
            int op = __shfl_xor(wp, s, 64);
            bool rep = (od < wd) || (od == wd && op < wp);
            wd = rep ? od : wd; wp = rep ? op : wp;
        }
        res = (lane == it) ? wp : res;
        if (bp == wp) {
            int slot = ba;
            if (slot < 32) elo |= (1u << slot); else ehi |= (1u << (slot - 32));
            int g = slot >> 3;
            switch (g) {
                case 0: RESCAN(0) break;
                case 1: RESCAN(1) break;
                case 2: RESCAN(2) break;
                case 3: RESCAN(3) break;
                case 4: RESCAN(4) break;
                case 5: RESCAN(5) break;
                case 6: RESCAN(6) break;
                case 7: RESCAN(7) break;
            }
        }
    }
    if (lane < KK) nidx[(size_t)bm * KK + lane] = res;
}

// ---------------- gtemb max (output 2); reads raw temb dual-dtype
__global__ __launch_bounds__(256) void k_gtemb(
    const void* __restrict__ temb,   // [B][64][N] raw
    const int* __restrict__ nidx,
    void* __restrict__ d_out, const int* __restrict__ flag)
{
    __shared__ int nid[64][32];
    int b = blockIdx.y, m0 = blockIdx.x * 64;
    int tid = threadIdx.x;
    for (int t = tid; t < 64 * 32; t += 256)
        nid[t >> 5][t & 31] = nidx[(size_t)(b * MM + m0) * 32 + t] & (NN - 1);
    __syncthreads();
    int c = tid & 63, mg = tid >> 6;
    int fl = *flag;
    size_t cbase = ((size_t)b * 64 + c) * NN;
#pragma unroll 1
    for (int s = 0; s < 16; s++) {
        int mm = mg * 16 + s;
        float best = -3.0e38f;
        if (fl) {
            const float* tb = (const float*)temb + cbase;
#pragma unroll
            for (int k = 0; k < 32; k++) best = fmaxf(best, tb[nid[mm][k]]);
        } else {
            const unsigned short* tb = (const unsigned short*)temb + cbase;
#pragma unroll
            for (int k = 0; k < 32; k++) best = fmaxf(best, bf2f(tb[nid[mm][k]]));
        }
        size_t off = (size_t)OUT2_OFF + (size_t)(b * 64 + c) * MM + m0 + mm;
        if (fl) ((float*)d_out)[off] = best;
        else    ((unsigned short*)d_out)[off] = f2bf(best);
    }
}

// ================= fused MLP machinery (raw feature gathers) =====
#define W1Tm(j,c)     (((float*)SM)[(j)*64+(c)])
#define GBUFm(mi,k,c) (((float*)(SM+17152))[(((mi)*32+(k))*66)+(c)])
#define GCm(mi,j,k)   (((float*)(SM+50944))[(((mi)*3+(j))*32)+(k)])
#define NDm(mi,k)     (((int*)(SM+52480))[((mi)*32)+(k)])
#define W2Tm(j,c)     (((float*)SM)[(j)*128+(c)])
#define ACTm(mi,j,k)  (((float*)(SM+32768))[(((mi)*64+(j))*32)+(k)])

#define P_W1 0
#define P_B1 4288
#define P_G1 4352
#define P_BE1 4416
#define P_W2 4480
#define P_B2 12672
#define P_G2 12800
#define P_BE2 12928

__device__ __forceinline__ void mlp1_compute(
    char* SM, int tid, int lane, int mi, int b, int bm, int fl,
    const void* __restrict__ feat, const float* __restrict__ coordsC,
    const float* __restrict__ centersF, const int* __restrict__ nidx,
    const float* __restrict__ P, float acc[8][4])
{
    for (int t = tid; t < 64 * 67; t += 256) {
        int c = t / 67, j = t % 67;
        W1Tm(j, c) = P[P_W1 + t];
    }
    if (lane < 32) NDm(mi, lane) = nidx[(size_t)bm * KK + lane] & (NN - 1);
    __syncthreads();
    size_t chb = ((size_t)b * 64 + lane) * NN;
    if (fl) {
        const float* fp = (const float*)feat + chb;
#pragma unroll 4
        for (int q = 0; q < 32; q++) GBUFm(mi, q, lane) = fp[NDm(mi, q)];
    } else {
        const unsigned short* fp = (const unsigned short*)feat + chb;
#pragma unroll 4
        for (int q = 0; q < 32; q++) GBUFm(mi, q, lane) = bf2f(fp[NDm(mi, q)]);
    }
    float4 ctr = *(const float4*)(centersF + (size_t)bm * 4);
    const float* cb = coordsC + (size_t)b * 3 * NN;
    if (lane < 32) {
        int n = NDm(mi, lane);
        GCm(mi, 0, lane) = __fsub_rn(cb[n], ctr.x);
        GCm(mi, 1, lane) = __fsub_rn(cb[NN + n], ctr.y);
        GCm(mi, 2, lane) = __fsub_rn(cb[2 * NN + n], ctr.z);
    }
    __syncthreads();
    int c0 = (lane >> 3) * 8;
    int k0 = (lane & 7) * 4;
#pragma unroll
    for (int i = 0; i < 8; i++)
#pragma unroll
        for (int kk = 0; kk < 4; kk++) acc[i][kk] = 0.f;
#pragma unroll
    for (int j = 0; j < 3; j++) {
        float4 a = *(const float4*)&GCm(mi, j, k0);
        float4 w0 = *(const float4*)&W1Tm(j, c0);
        float4 w1v = *(const float4*)&W1Tm(j, c0 + 4);
        float w[8] = {w0.x, w0.y, w0.z, w0.w, w1v.x, w1v.y, w1v.z, w1v.w};
#pragma unroll
        for (int i = 0; i < 8; i++) {
            acc[i][0] = fmaf(w[i], a.x, acc[i][0]);
            acc[i][1] = fmaf(w[i], a.y, acc[i][1]);
            acc[i][2] = fmaf(w[i], a.z, acc[i][2]);
            acc[i][3] = fmaf(w[i], a.w, acc[i][3]);
        }
    }
#pragma unroll 4
    for (int c = 0; c < 64; c++) {
        float f0 = GBUFm(mi, k0 + 0, c);
        float f1 = GBUFm(mi, k0 + 1, c);
        float f2 = GBUFm(mi, k0 + 2, c);
        float f3 = GBUFm(mi, k0 + 3, c);
        int j = 3 + c;
        float4 w0 = *(const float4*)&W1Tm(j, c0);
        float4 w1v = *(const float4*)&W1Tm(j, c0 + 4);
        float w[8] = {w0.x, w0.y, w0.z, w0.w, w1v.x, w1v.y, w1v.z, w1v.w};
#pragma unroll
        for (int i = 0; i < 8; i++) {
            acc[i][0] = fmaf(w[i], f0, acc[i][0]);
            acc[i][1] = fmaf(w[i], f1, acc[i][1]);
            acc[i][2] = fmaf(w[i], f2, acc[i][2]);
            acc[i][3] = fmaf(w[i], f3, acc[i][3]);
        }
    }
}

__device__ __forceinline__ void mlp2_compute(
    char* SM, int tid, int lane, int mi, int b,
    const float acc1[8][4], const float* __restrict__ coef1,
    const float* __restrict__ P, float acc2[16][4])
{
    __syncthreads();  // phase1 LDS dead
    int c0 = (lane >> 3) * 8;
    int k0 = (lane & 7) * 4;
#pragma unroll
    for (int i = 0; i < 8; i++) {
        int c = c0 + i;
        float sc = coef1[(b * 64 + c) * 2];
        float sh = coef1[(b * 64 + c) * 2 + 1];
        float bb = P[P_B1 + c];
#pragma unroll
        for (int kk = 0; kk < 4; kk++)
            ACTm(mi, c, k0 + kk) = swishf(fmaf(acc1[i][kk] + bb, sc, sh));
    }
    for (int t = tid; t < 128 * 64; t += 256) {
        int c = t >> 6, j = t & 63;
        W2Tm(j, c) = P[P_W2 + t];
    }
    __syncthreads();
    int c02 = (lane >> 3) * 16;
#pragma unroll
    for (int i = 0; i < 16; i++)
#pragma unroll
        for (int kk = 0; kk < 4; kk++) acc2[i][kk] = 0.f;
#pragma unroll 4
    for (int j = 0; j < 64; j++) {
        float4 a = *(const float4*)&ACTm(mi, j, k0);
        float4 w0 = *(const float4*)&W2Tm(j, c02);
        float4 w1v = *(const float4*)&W2Tm(j, c02 + 4);
        float4 w2v = *(const float4*)&W2Tm(j, c02 + 8);
        float4 w3 = *(const float4*)&W2Tm(j, c02 + 12);
        float w[16] = {w0.x, w0.y, w0.z, w0.w, w1v.x, w1v.y, w1v.z, w1v.w,
                       w2v.x, w2v.y, w2v.z, w2v.w, w3.x, w3.y, w3.z, w3.w};
#pragma unroll
        for (int i = 0; i < 16; i++) {
            acc2[i][0] = fmaf(w[i], a.x, acc2[i][0]);
            acc2[i][1] = fmaf(w[i], a.y, acc2[i][1]);
            acc2[i][2] = fmaf(w[i], a.z, acc2[i][2]);
            acc2[i][3] = fmaf(w[i], a.w, acc2[i][3]);
        }
    }
}

// ---------------- MLP1 + GN1 block-partial stats
__global__ __launch_bounds__(256) void k_mlp1s(
    const void* __restrict__ feat, const float* __restrict__ coordsC,
    const float* __restrict__ centersF, const int* __restrict__ nidx,
    const float* __restrict__ P, float* __restrict__ part1,
    const int* __restrict__ flag)
{
    __shared__ __align__(16) char smem[53248];
    char* SM = smem;
    int tid = threadIdx.x, blk = blockIdx.x;
    int b = blk >> 8, m0 = (blk & 255) * 4;
    int mi = tid >> 6, lane = tid & 63;
    int bm = b * MM + m0 + mi;
    int fl = *flag;
    float acc[8][4];
    mlp1_compute(SM, tid, lane, mi, b, bm, fl, feat, coordsC, centersF, nidx, P, acc);
    int c0 = (lane >> 3) * 8;
    float s = 0.f, s2 = 0.f;
#pragma unroll
    for (int i = 0; i < 8; i++) {
        float bb = P[P_B1 + c0 + i];
#pragma unroll
        for (int kk = 0; kk < 4; kk++) {
            float v = acc[i][kk] + bb;
            s += v; s2 = fmaf(v, v, s2);
        }
    }
    s += __shfl_xor(s, 1, 64); s += __shfl_xor(s, 2, 64); s += __shfl_xor(s, 4, 64);
    s2 += __shfl_xor(s2, 1, 64); s2 += __shfl_xor(s2, 2, 64); s2 += __shfl_xor(s2, 4, 64);
    float* sred = (float*)(SM + 52992);
    __syncthreads();
    if ((lane & 7) == 0) {
        int g = lane >> 3;
        sred[(mi * 8 + g) * 2] = s;
        sred[(mi * 8 + g) * 2 + 1] = s2;
    }
    __syncthreads();
    if (tid < 16) {
        int g = tid >> 1, w = tid & 1;
        float t = sred[(0 * 8 + g) * 2 + w] + sred[(1 * 8 + g) * 2 + w]
                + sred[(2 * 8 + g) * 2 + w] + sred[(3 * 8 + g) * 2 + w];
        part1[blk * 16 + g * 2 + w] = t;
    }
}

__global__ void k_coef1(const float* __restrict__ part1, const float* __restrict__ P,
                        float* __restrict__ coef1) {
    int t = threadIdx.x;
    int b = t >> 3, g = t & 7;
    float S = 0.f, Q = 0.f;
    for (int r = 0; r < 256; r++) {
        S += part1[(b * 256 + r) * 16 + g * 2];
        Q += part1[(b * 256 + r) * 16 + g * 2 + 1];
    }
    float inv_n = 1.0f / 262144.0f;
    float mean = S * inv_n;
    float var = Q * inv_n - mean * mean;
    float inv = rsqrtf(var + 1e-5f);
    for (int i = 0; i < 8; i++) {
        int c = g * 8 + i;
        float sc = P[P_G1 + c] * inv;
        coef1[(b * 64 + c) * 2] = sc;
        coef1[(b * 64 + c) * 2 + 1] = P[P_BE1 + c] - mean * sc;
    }
}

// ---------------- MLP1+act+MLP2 + GN2 block-partial stats
__global__ __launch_bounds__(256) void k_mlp2s(
    const void* __restrict__ feat, const float* __restrict__ coordsC,
    const float* __restrict__ centersF, const int* __restrict__ nidx,
    const float* __restrict__ P, const float* __restrict__ coef1,
    float* __restrict__ part2, const int* __restrict__ flag)
{
    __shared__ __align__(16) char smem[65536];
    char* SM = smem;
    int tid = threadIdx.x, blk = blockIdx.x;
    int b = blk >> 8, m0 = (blk & 255) * 4;
    int mi = tid >> 6, lane = tid & 63;
    int bm = b * MM + m0 + mi;
    int fl = *flag;
    float acc1[8][4];
    mlp1_compute(SM, tid, lane, mi, b, bm, fl, feat, coordsC, centersF, nidx, P, acc1);
    float acc2[16][4];
    mlp2_compute(SM, tid, lane, mi, b, acc1, coef1, P, acc2);
    int c02 = (lane >> 3) * 16;
    float s = 0.f, s2 = 0.f;
#pragma unroll
    for (int i = 0; i < 16; i++) {
        float bb = P[P_B2 + c02 + i];
#pragma unroll
        for (int kk = 0; kk < 4; kk++) {
            float v = acc2[i][kk] + bb;
            s += v; s2 = fmaf(v, v, s2);
        }
    }
    s += __shfl_xor(s, 1, 64); s += __shfl_xor(s, 2, 64); s += __shfl_xor(s, 4, 64);
    s2 += __shfl_xor(s2, 1, 64); s2 += __shfl_xor(s2, 2, 64); s2 += __shfl_xor(s2, 4, 64);
    __syncthreads();  // phase2 LDS dead
    float* sred = (float*)SM;
    if ((lane & 7) == 0) {
        int g = lane >> 3;
        sred[(mi * 8 + g) * 2] = s;
        sred[(mi * 8 + g) * 2 + 1] = s2;
    }
    __syncthreads();
    if (tid < 16) {
        int g = tid >> 1, w = tid & 1;
        float t = sred[(0 * 8 + g) * 2 + w] + sred[(1 * 8 + g) * 2 + w]
                + sred[(2 * 8 + g) * 2 + w] + sred[(3 * 8 + g) * 2 + w];
        part2[blk * 16 + g * 2 + w] = t;
    }
}

__global__ void k_coef2(const float* __restrict__ part2, const float* __restrict__ P,
                        float* __restrict__ coef2) {
    int t = threadIdx.x;
    int b = t >> 3, g = t & 7;
    float S = 0.f, Q = 0.f;
    for (int r = 0; r < 256; r++) {
        S += part2[(b * 256 + r) * 16 + g * 2];
        Q += part2[(b * 256 + r) * 16 + g * 2 + 1];
    }
    float inv_n = 1.0f / 524288.0f;
    float mean = S * inv_n;
    float var = Q * inv_n - mean * mean;
    float inv = rsqrtf(var + 1e-5f);
    for (int i = 0; i < 16; i++) {
        int c = g * 16 + i;
        float sc = P[P_G2 + c] * inv;
        coef2[(b * 128 + c) * 2] = sc;
        coef2[(b * 128 + c) * 2 + 1] = P[P_BE2 + c] - mean * sc;
    }
}

// ---------------- final: recompute, swish(GN2), max over K -> out0
__global__ __launch_bounds__(256) void k_final(
    const void* __restrict__ feat, const float* __restrict__ coordsC,
    const float* __restrict__ centersF, const int* __restrict__ nidx,
    const float* __restrict__ P, const float* __restrict__ coef1,
    const float* __restrict__ coef2,
    void* __restrict__ d_out, const int* __restrict__ flag)
{
    __shared__ __align__(16) char smem[65536];
    char* SM = smem;
    int tid = threadIdx.x, blk = blockIdx.x;
    int b = blk >> 8, m0 = (blk & 255) * 4;
    int mi = tid >> 6, lane = tid & 63;
    int bm = b * MM + m0 + mi;
    int fl = *flag;
    float acc1[8][4];
    mlp1_compute(SM, tid, lane, mi, b, bm, fl, feat, coordsC, centersF, nidx, P, acc1);
    float acc2[16][4];
    mlp2_compute(SM, tid, lane, mi, b, acc1, coef1, P, acc2);
    int c02 = (lane >> 3) * 16;
    float mx[16];
#pragma unroll
    for (int i = 0; i < 16; i++) {
        int c = c02 + i;
        float sc = coef2[(b * 128 + c) * 2];
        float sh = coef2[(b * 128 + c) * 2 + 1];
        float bb = P[P_B2 + c];
        float v = -3.0e38f;
#pragma unroll
        for (int kk = 0; kk < 4; kk++)
            v = fmaxf(v, swishf(fmaf(acc2[i][kk] + bb, sc, sh)));
        v = fmaxf(v, __shfl_xor(v, 1, 64));
        v = fmaxf(v, __shfl_xor(v, 2, 64));
        v = fmaxf(v, __shfl_xor(v, 4, 64));
        mx[i] = v;
    }
    if ((lane & 7) == 0) {
        int m = m0 + mi;
#pragma unroll
        for (int i = 0; i < 16; i++) {
            size_t off = (size_t)(b * 128 + c02 + i) * MM + m;
            if (fl) ((float*)d_out)[off] = mx[i];
            else    ((unsigned short*)d_out)[off] = f2bf(mx[i]);
        }
    }
}

extern "C" void kernel_launch(void* const* d_in, const int* in_sizes, int n_in,
                              void* d_out, int out_size, void* d_ws, size_t ws_size,
                              hipStream_t stream) {
    (void)in_sizes; (void)n_in; (void)out_size; (void)ws_size;
    const void* feat = d_in[0];
    const void* coords = d_in[1];
    const void* temb = d_in[2];

    // compact workspace: ~1.9 MB total
    char* ws = (char*)d_ws;
    int* flag = (int*)ws;                                  // @0 (64 B reserved)
    float* coordsC = (float*)(ws + 64);                    // 393,216
    float* paramsC = (float*)(ws + 393280);                // 52,224
    float* centersF = (float*)(ws + 445504);               // 131,072
    int* nidx = (int*)(ws + 576576);                       // 1,048,576
    float* part1 = (float*)(ws + 1625152);                 // 131,072
    float* part2 = (float*)(ws + 1756224);                 // 131,072
    float* coef1 = (float*)(ws + 1887296);                 // 4,096
    float* coef2 = (float*)(ws + 1891392);                 // 8,192 -> ends 1,899,584

    k_detect<<<1, 64, 0, stream>>>((const unsigned short*)feat, flag);
    k_cvt<<<384, 256, 0, stream>>>(coords, coordsC, flag, BB * 3 * NN);
    k_cvt_params<<<51, 256, 0, stream>>>(d_in[3], d_in[4], d_in[5], d_in[6],
                                         d_in[7], d_in[8], d_in[9], d_in[10],
                                         paramsC, flag);
    k_fps<<<8, 1024, 0, stream>>>(coordsC, centersF, d_out, flag);
    k_knn<<<8192, 64, 0, stream>>>(coordsC, centersF, nidx);
    k_gtemb<<<dim3(16, 8), 256, 0, stream>>>(temb, nidx, d_out, flag);
    k_mlp1s<<<2048, 256, 0, stream>>>(feat, coordsC, centersF, nidx, paramsC, part1, flag);
    k_coef1<<<1, 64, 0, stream>>>(part1, paramsC, coef1);
    k_mlp2s<<<2048, 256, 0, stream>>>(feat, coordsC, centersF, nidx, paramsC, coef1, part2, flag);
    k_coef2<<<1, 64, 0, stream>>>(part2, paramsC, coef2);
    k_final<<<2048, 256, 0, stream>>>(feat, coordsC, centersF, nidx, paramsC, coef1, coef2, d_out, flag);
}

// Round 6
// 1956.713 us; speedup vs baseline: 1.5597x; 1.5597x over previous
//
#include <hip/hip_runtime.h>
#include <stdint.h>

#define BB 8
#define NN 4096
#define MM 1024
#define KK 32

__device__ __forceinline__ float bf2f(unsigned short u) {
    union { unsigned int i; float f; } v; v.i = ((unsigned int)u) << 16; return v.f;
}
__device__ __forceinline__ unsigned short f2bf(float f) {
    union { float f; unsigned int i; } v; v.f = f;
    unsigned int x = v.i;
    x += 0x7fffu + ((x >> 16) & 1u);
    return (unsigned short)(x >> 16);
}
__device__ __forceinline__ float swishf(float y) {
    return __fdividef(y, 1.0f + __expf(-y));
}

// out element offsets (dtype-independent)
#define OUT0_OFF 0
#define OUT1_OFF 1048576
#define OUT2_OFF 1073152

// ---------------- dtype probe: even-index ushorts of features.
__global__ void k_detect(const unsigned short* __restrict__ f, int* __restrict__ flag) {
    int lane = threadIdx.x;
    unsigned short u = f[lane * 2];
    float x = fabsf(bf2f(u));
    bool ext = (u != 0) && (x > 100.0f || x < 1e-30f);
    unsigned long long m = __ballot(ext);
    if (lane == 0) *flag = (__popcll(m) >= 16) ? 1 : 0;
}

// ---------------- generic convert (coords)
__global__ __launch_bounds__(256) void k_cvt(
    const void* __restrict__ src, float* __restrict__ dst,
    const int* __restrict__ flag, int n)
{
    int idx = blockIdx.x * 256 + threadIdx.x;
    if (idx >= n) return;
    dst[idx] = (*flag) ? ((const float*)src)[idx]
                       : bf2f(((const unsigned short*)src)[idx]);
}

// ---------------- params convert into one canonical f32 buffer
__global__ __launch_bounds__(256) void k_cvt_params(
    const void* W1, const void* b1, const void* g1, const void* be1,
    const void* W2, const void* b2, const void* g2, const void* be2,
    float* __restrict__ dst, const int* __restrict__ flag)
{
    int idx = blockIdx.x * 256 + threadIdx.x;
    if (idx >= 13056) return;
    const void* src; int off;
    if (idx < 4288)       { src = W1;  off = idx; }
    else if (idx < 4352)  { src = b1;  off = idx - 4288; }
    else if (idx < 4416)  { src = g1;  off = idx - 4352; }
    else if (idx < 4480)  { src = be1; off = idx - 4416; }
    else if (idx < 12672) { src = W2;  off = idx - 4480; }
    else if (idx < 12800) { src = b2;  off = idx - 12672; }
    else if (idx < 12928) { src = g2;  off = idx - 12800; }
    else                  { src = be2; off = idx - 12928; }
    dst[idx] = (*flag) ? ((const float*)src)[off]
                       : bf2f(((const unsigned short*)src)[off]);
}

// ---------------- FPS in f64, latency-optimized:
// 256 thr (4 waves), 16 contiguous pts/thread; coords staged in LDS;
// fused min-update + local argmax; 1 barrier/step (parity buffers).
// block=256: 16-wave version measured 2.1 us/step (barrier laggards +
// global far-point loads on the critical path); 4 waves + LDS coords
// cuts both.
__global__ __launch_bounds__(256) void k_fps(
    const float* __restrict__ coordsC,  // [B][3][N] (f32, exact bf16)
    float* __restrict__ centersF,       // [B][M][4] x,y,z,0
    void* __restrict__ d_out, const int* __restrict__ flag)
{
    __shared__ float xs[NN], ys[NN], zs[NN];
    __shared__ int hist[MM];
    __shared__ double pb[2][8];
    __shared__ int pi[2][8];
    int b = blockIdx.x;
    int t = threadIdx.x;
    const float* cb = coordsC + (size_t)b * 3 * NN;
#pragma unroll
    for (int i = 0; i < 16; i++) {
        int p = t + i * 256;
        xs[p] = cb[p]; ys[p] = cb[NN + p]; zs[p] = cb[2 * NN + p];
    }
    if (t == 0) hist[0] = 0;
    __syncthreads();
    int base = t * 16;
    double px[16], py[16], pz[16], dist[16];
    double x0 = (double)xs[0], y0 = (double)ys[0], z0 = (double)zs[0];
    double bd = -1.0; int bp = base;
#pragma unroll
    for (int j = 0; j < 16; j++) {
        px[j] = (double)xs[base + j]; py[j] = (double)ys[base + j]; pz[j] = (double)zs[base + j];
        double dx = px[j] - x0, dy = py[j] - y0, dz = pz[j] - z0;
        dist[j] = fma(dz, dz, fma(dy, dy, dx * dx));
        bool rep = dist[j] > bd;
        bd = rep ? dist[j] : bd; bp = rep ? base + j : bp;
    }
    int lane = t & 63, wid = t >> 6;
#pragma unroll 1
    for (int s = 1; s < MM; s++) {
        // wave butterfly: max dist, tie -> min idx
#pragma unroll
        for (int m = 32; m >= 1; m >>= 1) {
            double od = __shfl_xor(bd, m, 64);
            int op = __shfl_xor(bp, m, 64);
            bool rep = (od > bd) || (od == bd && op < bp);
            bd = rep ? od : bd; bp = rep ? op : bp;
        }
        int par = s & 1;
        if (lane == 0) { pb[par][wid] = bd; pi[par][wid] = bp; }
        __syncthreads();
        double wd = pb[par][0]; int wp = pi[par][0];
#pragma unroll
        for (int w = 1; w < 4; w++) {
            double od = pb[par][w]; int op = pi[par][w];
            bool rep = (od > wd) || (od == wd && op < wp);
            wd = rep ? od : wd; wp = rep ? op : wp;
        }
        if (t == 0) hist[s] = wp;
        double fx = (double)xs[wp], fy = (double)ys[wp], fz = (double)zs[wp];
        // fused update + next local argmax
        bd = -1.0; bp = base;
#pragma unroll
        for (int j = 0; j < 16; j++) {
            double dx = px[j] - fx, dy = py[j] - fy, dz = pz[j] - fz;
            double d = fma(dz, dz, fma(dy, dy, dx * dx));
            dist[j] = fmin(dist[j], d);
            bool rep = dist[j] > bd;
            bd = rep ? dist[j] : bd; bp = rep ? base + j : bp;
        }
    }
    __syncthreads();
    int fl = *flag;
    size_t o1 = OUT1_OFF;
#pragma unroll
    for (int i = 0; i < 4; i++) {
        int m = t + i * 256;
        int far = hist[m];
        float X = xs[far], Y = ys[far], Z = zs[far];
        if (fl) {
            float* o = (float*)d_out;
            o[o1 + (size_t)(b * 3 + 0) * MM + m] = X;
            o[o1 + (size_t)(b * 3 + 1) * MM + m] = Y;
            o[o1 + (size_t)(b * 3 + 2) * MM + m] = Z;
        } else {
            unsigned short* o = (unsigned short*)d_out;
            o[o1 + (size_t)(b * 3 + 0) * MM + m] = f2bf(X);
            o[o1 + (size_t)(b * 3 + 1) * MM + m] = f2bf(Y);
            o[o1 + (size_t)(b * 3 + 2) * MM + m] = f2bf(Z);
        }
        *(float4*)(centersF + ((size_t)b * MM + m) * 4) = make_float4(X, Y, Z, 0.f);
    }
}

// ---------------- kNN in f64 (mirrors np float64 golden expansion):
// d = (cc + pp) - 2*dot, K=32 smallest by (d, idx) lex. 1 wave per center.
#define RESCAN(G) { \
    double gd = 1.0e300; int ga = (G) * 8; \
    _Pragma("unroll") \
    for (int i = 0; i < 8; i++) { \
        int sl = (G) * 8 + i; \
        unsigned int bit = (sl < 32) ? (elo >> sl) : (ehi >> (sl - 32)); \
        double cd = (bit & 1u) ? 1.0e300 : d[sl]; \
        bool rep = cd < gd; \
        gd = rep ? cd : gd; ga = rep ? sl : ga; \
    } \
    g8[(G)] = gd; a8[(G)] = ga; }

__global__ __launch_bounds__(64, 1) void k_knn(
    const float* __restrict__ coordsC,
    const float* __restrict__ centersF,
    int* __restrict__ nidx)
{
    int bm = blockIdx.x;
    int b = bm >> 10;
    int lane = threadIdx.x;
    const float* cb = coordsC + (size_t)b * 3 * NN;
    float4 ctr = *(const float4*)(centersF + (size_t)bm * 4);
    double cx = (double)ctr.x, cy = (double)ctr.y, cz = (double)ctr.z;
    double cc = (cx * cx + cy * cy) + cz * cz;
    double d[64];
#pragma unroll 4
    for (int j = 0; j < 64; j++) {
        int p = j * 64 + lane;
        double x = (double)cb[p], y = (double)cb[NN + p], z = (double)cb[2 * NN + p];
        double pp = (x * x + y * y) + z * z;
        double dt = (cx * x + cy * y) + cz * z;
        d[j] = (cc + pp) - 2.0 * dt;
    }
    double g8[8]; int a8[8];
#pragma unroll
    for (int g = 0; g < 8; g++) {
        double gd = d[g * 8]; int ga = g * 8;
#pragma unroll
        for (int i = 1; i < 8; i++) {
            int sl = g * 8 + i;
            bool rep = d[sl] < gd;
            gd = rep ? d[sl] : gd; ga = rep ? sl : ga;
        }
        g8[g] = gd; a8[g] = ga;
    }
    unsigned int elo = 0, ehi = 0;
    int res = 0;
#pragma unroll 1
    for (int it = 0; it < 32; it++) {
        double bd = g8[0]; int ba = a8[0];
#pragma unroll
        for (int g = 1; g < 8; g++) {
            bool rep = g8[g] < bd;
            bd = rep ? g8[g] : bd; ba = rep ? a8[g] : ba;
        }
        int bp = ba * 64 + lane;
        double wd = bd; int wp = bp;
#pragma unroll
        for (int s = 32; s >= 1; s >>= 1) {
            double od = __shfl_xor(wd, s, 64);
            int op = __shfl_xor(wp, s, 64);
            bool rep = (od < wd) || (od == wd && op < wp);
            wd = rep ? od : wd; wp = rep ? op : wp;
        }
        res = (lane == it) ? wp : res;
        if (bp == wp) {
            int slot = ba;
            if (slot < 32) elo |= (1u << slot); else ehi |= (1u << (slot - 32));
            int g = slot >> 3;
            switch (g) {
                case 0: RESCAN(0) break;
                case 1: RESCAN(1) break;
                case 2: RESCAN(2) break;
                case 3: RESCAN(3) break;
                case 4: RESCAN(4) break;
                case 5: RESCAN(5) break;
                case 6: RESCAN(6) break;
                case 7: RESCAN(7) break;
            }
        }
    }
    if (lane < KK) nidx[(size_t)bm * KK + lane] = res;
}

// ---------------- gtemb max (output 2); reads raw temb dual-dtype
__global__ __launch_bounds__(256) void k_gtemb(
    const void* __restrict__ temb,   // [B][64][N] raw
    const int* __restrict__ nidx,
    void* __restrict__ d_out, const int* __restrict__ flag)
{
    __shared__ int nid[64][32];
    int b = blockIdx.y, m0 = blockIdx.x * 64;
    int tid = threadIdx.x;
    for (int t = tid; t < 64 * 32; t += 256)
        nid[t >> 5][t & 31] = nidx[(size_t)(b * MM + m0) * 32 + t] & (NN - 1);
    __syncthreads();
    int c = tid & 63, mg = tid >> 6;
    int fl = *flag;
    size_t cbase = ((size_t)b * 64 + c) * NN;
#pragma unroll 1
    for (int s = 0; s < 16; s++) {
        int mm = mg * 16 + s;
        float best = -3.0e38f;
        if (fl) {
            const float* tb = (const float*)temb + cbase;
#pragma unroll
            for (int k = 0; k < 32; k++) best = fmaxf(best, tb[nid[mm][k]]);
        } else {
            const unsigned short* tb = (const unsigned short*)temb + cbase;
#pragma unroll
            for (int k = 0; k < 32; k++) best = fmaxf(best, bf2f(tb[nid[mm][k]]));
        }
        size_t off = (size_t)OUT2_OFF + (size_t)(b * 64 + c) * MM + m0 + mm;
        if (fl) ((float*)d_out)[off] = best;
        else    ((unsigned short*)d_out)[off] = f2bf(best);
    }
}

// ================= fused MLP machinery (raw feature gathers) =====
#define W1Tm(j,c)     (((float*)SM)[(j)*64+(c)])
#define GBUFm(mi,k,c) (((float*)(SM+17152))[(((mi)*32+(k))*66)+(c)])
#define GCm(mi,j,k)   (((float*)(SM+50944))[(((mi)*3+(j))*32)+(k)])
#define NDm(mi,k)     (((int*)(SM+52480))[((mi)*32)+(k)])
#define W2Tm(j,c)     (((float*)SM)[(j)*128+(c)])
#define ACTm(mi,j,k)  (((float*)(SM+32768))[(((mi)*64+(j))*32)+(k)])

#define P_W1 0
#define P_B1 4288
#define P_G1 4352
#define P_BE1 4416
#define P_W2 4480
#define P_B2 12672
#define P_G2 12800
#define P_BE2 12928

__device__ __forceinline__ void mlp1_compute(
    char* SM, int tid, int lane, int mi, int b, int bm, int fl,
    const void* __restrict__ feat, const float* __restrict__ coordsC,
    const float* __restrict__ centersF, const int* __restrict__ nidx,
    const float* __restrict__ P, float acc[8][4])
{
    for (int t = tid; t < 64 * 67; t += 256) {
        int c = t / 67, j = t % 67;
        W1Tm(j, c) = P[P_W1 + t];
    }
    if (lane < 32) NDm(mi, lane) = nidx[(size_t)bm * KK + lane] & (NN - 1);
    __syncthreads();
    size_t chb = ((size_t)b * 64 + lane) * NN;
    if (fl) {
        const float* fp = (const float*)feat + chb;
#pragma unroll 4
        for (int q = 0; q < 32; q++) GBUFm(mi, q, lane) = fp[NDm(mi, q)];
    } else {
        const unsigned short* fp = (const unsigned short*)feat + chb;
#pragma unroll 4
        for (int q = 0; q < 32; q++) GBUFm(mi, q, lane) = bf2f(fp[NDm(mi, q)]);
    }
    float4 ctr = *(const float4*)(centersF + (size_t)bm * 4);
    const float* cb = coordsC + (size_t)b * 3 * NN;
    if (lane < 32) {
        int n = NDm(mi, lane);
        GCm(mi, 0, lane) = __fsub_rn(cb[n], ctr.x);
        GCm(mi, 1, lane) = __fsub_rn(cb[NN + n], ctr.y);
        GCm(mi, 2, lane) = __fsub_rn(cb[2 * NN + n], ctr.z);
    }
    __syncthreads();
    int c0 = (lane >> 3) * 8;
    int k0 = (lane & 7) * 4;
#pragma unroll
    for (int i = 0; i < 8; i++)
#pragma unroll
        for (int kk = 0; kk < 4; kk++) acc[i][kk] = 0.f;
#pragma unroll
    for (int j = 0; j < 3; j++) {
        float4 a = *(const float4*)&GCm(mi, j, k0);
        float4 w0 = *(const float4*)&W1Tm(j, c0);
        float4 w1v = *(const float4*)&W1Tm(j, c0 + 4);
        float w[8] = {w0.x, w0.y, w0.z, w0.w, w1v.x, w1v.y, w1v.z, w1v.w};
#pragma unroll
        for (int i = 0; i < 8; i++) {
            acc[i][0] = fmaf(w[i], a.x, acc[i][0]);
            acc[i][1] = fmaf(w[i], a.y, acc[i][1]);
            acc[i][2] = fmaf(w[i], a.z, acc[i][2]);
            acc[i][3] = fmaf(w[i], a.w, acc[i][3]);
        }
    }
#pragma unroll 4
    for (int c = 0; c < 64; c++) {
        float f0 = GBUFm(mi, k0 + 0, c);
        float f1 = GBUFm(mi, k0 + 1, c);
        float f2 = GBUFm(mi, k0 + 2, c);
        float f3 = GBUFm(mi, k0 + 3, c);
        int j = 3 + c;
        float4 w0 = *(const float4*)&W1Tm(j, c0);
        float4 w1v = *(const float4*)&W1Tm(j, c0 + 4);
        float w[8] = {w0.x, w0.y, w0.z, w0.w, w1v.x, w1v.y, w1v.z, w1v.w};
#pragma unroll
        for (int i = 0; i < 8; i++) {
            acc[i][0] = fmaf(w[i], f0, acc[i][0]);
            acc[i][1] = fmaf(w[i], f1, acc[i][1]);
            acc[i][2] = fmaf(w[i], f2, acc[i][2]);
            acc[i][3] = fmaf(w[i], f3, acc[i][3]);
        }
    }
}

__device__ __forceinline__ void mlp2_compute(
    char* SM, int tid, int lane, int mi, int b,
    const float acc1[8][4], const float* __restrict__ coef1,
    const float* __restrict__ P, float acc2[16][4])
{
    __syncthreads();  // phase1 LDS dead
    int c0 = (lane >> 3) * 8;
    int k0 = (lane & 7) * 4;
#pragma unroll
    for (int i = 0; i < 8; i++) {
        int c = c0 + i;
        float sc = coef1[(b * 64 + c) * 2];
        float sh = coef1[(b * 64 + c) * 2 + 1];
        float bb = P[P_B1 + c];
#pragma unroll
        for (int kk = 0; kk < 4; kk++)
            ACTm(mi, c, k0 + kk) = swishf(fmaf(acc1[i][kk] + bb, sc, sh));
    }
    for (int t = tid; t < 128 * 64; t += 256) {
        int c = t >> 6, j = t & 63;
        W2Tm(j, c) = P[P_W2 + t];
    }
    __syncthreads();
    int c02 = (lane >> 3) * 16;
#pragma unroll
    for (int i = 0; i < 16; i++)
#pragma unroll
        for (int kk = 0; kk < 4; kk++) acc2[i][kk] = 0.f;
#pragma unroll 4
    for (int j = 0; j < 64; j++) {
        float4 a = *(const float4*)&ACTm(mi, j, k0);
        float4 w0 = *(const float4*)&W2Tm(j, c02);
        float4 w1v = *(const float4*)&W2Tm(j, c02 + 4);
        float4 w2v = *(const float4*)&W2Tm(j, c02 + 8);
        float4 w3 = *(const float4*)&W2Tm(j, c02 + 12);
        float w[16] = {w0.x, w0.y, w0.z, w0.w, w1v.x, w1v.y, w1v.z, w1v.w,
                       w2v.x, w2v.y, w2v.z, w2v.w, w3.x, w3.y, w3.z, w3.w};
#pragma unroll
        for (int i = 0; i < 16; i++) {
            acc2[i][0] = fmaf(w[i], a.x, acc2[i][0]);
            acc2[i][1] = fmaf(w[i], a.y, acc2[i][1]);
            acc2[i][2] = fmaf(w[i], a.z, acc2[i][2]);
            acc2[i][3] = fmaf(w[i], a.w, acc2[i][3]);
        }
    }
}

// ---------------- MLP1 + GN1 block-partial stats
__global__ __launch_bounds__(256) void k_mlp1s(
    const void* __restrict__ feat, const float* __restrict__ coordsC,
    const float* __restrict__ centersF, const int* __restrict__ nidx,
    const float* __restrict__ P, float* __restrict__ part1,
    const int* __restrict__ flag)
{
    __shared__ __align__(16) char smem[53248];
    char* SM = smem;
    int tid = threadIdx.x, blk = blockIdx.x;
    int b = blk >> 8, m0 = (blk & 255) * 4;
    int mi = tid >> 6, lane = tid & 63;
    int bm = b * MM + m0 + mi;
    int fl = *flag;
    float acc[8][4];
    mlp1_compute(SM, tid, lane, mi, b, bm, fl, feat, coordsC, centersF, nidx, P, acc);
    int c0 = (lane >> 3) * 8;
    float s = 0.f, s2 = 0.f;
#pragma unroll
    for (int i = 0; i < 8; i++) {
        float bb = P[P_B1 + c0 + i];
#pragma unroll
        for (int kk = 0; kk < 4; kk++) {
            float v = acc[i][kk] + bb;
            s += v; s2 = fmaf(v, v, s2);
        }
    }
    s += __shfl_xor(s, 1, 64); s += __shfl_xor(s, 2, 64); s += __shfl_xor(s, 4, 64);
    s2 += __shfl_xor(s2, 1, 64); s2 += __shfl_xor(s2, 2, 64); s2 += __shfl_xor(s2, 4, 64);
    float* sred = (float*)(SM + 52992);
    __syncthreads();
    if ((lane & 7) == 0) {
        int g = lane >> 3;
        sred[(mi * 8 + g) * 2] = s;
        sred[(mi * 8 + g) * 2 + 1] = s2;
    }
    __syncthreads();
    if (tid < 16) {
        int g = tid >> 1, w = tid & 1;
        float t = sred[(0 * 8 + g) * 2 + w] + sred[(1 * 8 + g) * 2 + w]
                + sred[(2 * 8 + g) * 2 + w] + sred[(3 * 8 + g) * 2 + w];
        part1[blk * 16 + g * 2 + w] = t;
    }
}

__global__ void k_coef1(const float* __restrict__ part1, const float* __restrict__ P,
                        float* __restrict__ coef1) {
    int t = threadIdx.x;
    int b = t >> 3, g = t & 7;
    float S = 0.f, Q = 0.f;
    for (int r = 0; r < 256; r++) {
        S += part1[(b * 256 + r) * 16 + g * 2];
        Q += part1[(b * 256 + r) * 16 + g * 2 + 1];
    }
    float inv_n = 1.0f / 262144.0f;
    float mean = S * inv_n;
    float var = Q * inv_n - mean * mean;
    float inv = rsqrtf(var + 1e-5f);
    for (int i = 0; i < 8; i++) {
        int c = g * 8 + i;
        float sc = P[P_G1 + c] * inv;
        coef1[(b * 64 + c) * 2] = sc;
        coef1[(b * 64 + c) * 2 + 1] = P[P_BE1 + c] - mean * sc;
    }
}

// ---------------- MLP1+act+MLP2 + GN2 block-partial stats
__global__ __launch_bounds__(256) void k_mlp2s(
    const void* __restrict__ feat, const float* __restrict__ coordsC,
    const float* __restrict__ centersF, const int* __restrict__ nidx,
    const float* __restrict__ P, const float* __restrict__ coef1,
    float* __restrict__ part2, const int* __restrict__ flag)
{
    __shared__ __align__(16) char smem[65536];
    char* SM = smem;
    int tid = threadIdx.x, blk = blockIdx.x;
    int b = blk >> 8, m0 = (blk & 255) * 4;
    int mi = tid >> 6, lane = tid & 63;
    int bm = b * MM + m0 + mi;
    int fl = *flag;
    float acc1[8][4];
    mlp1_compute(SM, tid, lane, mi, b, bm, fl, feat, coordsC, centersF, nidx, P, acc1);
    float acc2[16][4];
    mlp2_compute(SM, tid, lane, mi, b, acc1, coef1, P, acc2);
    int c02 = (lane >> 3) * 16;
    float s = 0.f, s2 = 0.f;
#pragma unroll
    for (int i = 0; i < 16; i++) {
        float bb = P[P_B2 + c02 + i];
#pragma unroll
        for (int kk = 0; kk < 4; kk++) {
            float v = acc2[i][kk] + bb;
            s += v; s2 = fmaf(v, v, s2);
        }
    }
    s += __shfl_xor(s, 1, 64); s += __shfl_xor(s, 2, 64); s += __shfl_xor(s, 4, 64);
    s2 += __shfl_xor(s2, 1, 64); s2 += __shfl_xor(s2, 2, 64); s2 += __shfl_xor(s2, 4, 64);
    __syncthreads();  // phase2 LDS dead
    float* sred = (float*)SM;
    if ((lane & 7) == 0) {
        int g = lane >> 3;
        sred[(mi * 8 + g) * 2] = s;
        sred[(mi * 8 + g) * 2 + 1] = s2;
    }
    __syncthreads();
    if (tid < 16) {
        int g = tid >> 1, w = tid & 1;
        float t = sred[(0 * 8 + g) * 2 + w] + sred[(1 * 8 + g) * 2 + w]
                + sred[(2 * 8 + g) * 2 + w] + sred[(3 * 8 + g) * 2 + w];
        part2[blk * 16 + g * 2 + w] = t;
    }
}

__global__ void k_coef2(const float* __restrict__ part2, const float* __restrict__ P,
                        float* __restrict__ coef2) {
    int t = threadIdx.x;
    int b = t >> 3, g = t & 7;
    float S = 0.f, Q = 0.f;
    for (int r = 0; r < 256; r++) {
        S += part2[(b * 256 + r) * 16 + g * 2];
        Q += part2[(b * 256 + r) * 16 + g * 2 + 1];
    }
    float inv_n = 1.0f / 524288.0f;
    float mean = S * inv_n;
    float var = Q * inv_n - mean * mean;
    float inv = rsqrtf(var + 1e-5f);
    for (int i = 0; i < 16; i++) {
        int c = g * 16 + i;
        float sc = P[P_G2 + c] * inv;
        coef2[(b * 128 + c) * 2] = sc;
        coef2[(b * 128 + c) * 2 + 1] = P[P_BE2 + c] - mean * sc;
    }
}

// ---------------- final: recompute, swish(GN2), max over K -> out0
__global__ __launch_bounds__(256) void k_final(
    const void* __restrict__ feat, const float* __restrict__ coordsC,
    const float* __restrict__ centersF, const int* __restrict__ nidx,
    const float* __restrict__ P, const float* __restrict__ coef1,
    const float* __restrict__ coef2,
    void* __restrict__ d_out, const int* __restrict__ flag)
{
    __shared__ __align__(16) char smem[65536];
    char* SM = smem;
    int tid = threadIdx.x, blk = blockIdx.x;
    int b = blk >> 8, m0 = (blk & 255) * 4;
    int mi = tid >> 6, lane = tid & 63;
    int bm = b * MM + m0 + mi;
    int fl = *flag;
    float acc1[8][4];
    mlp1_compute(SM, tid, lane, mi, b, bm, fl, feat, coordsC, centersF, nidx, P, acc1);
    float acc2[16][4];
    mlp2_compute(SM, tid, lane, mi, b, acc1, coef1, P, acc2);
    int c02 = (lane >> 3) * 16;
    float mx[16];
#pragma unroll
    for (int i = 0; i < 16; i++) {
        int c = c02 + i;
        float sc = coef2[(b * 128 + c) * 2];
        float sh = coef2[(b * 128 + c) * 2 + 1];
        float bb = P[P_B2 + c];
        float v = -3.0e38f;
#pragma unroll
        for (int kk = 0; kk < 4; kk++)
            v = fmaxf(v, swishf(fmaf(acc2[i][kk] + bb, sc, sh)));
        v = fmaxf(v, __shfl_xor(v, 1, 64));
        v = fmaxf(v, __shfl_xor(v, 2, 64));
        v = fmaxf(v, __shfl_xor(v, 4, 64));
        mx[i] = v;
    }
    if ((lane & 7) == 0) {
        int m = m0 + mi;
#pragma unroll
        for (int i = 0; i < 16; i++) {
            size_t off = (size_t)(b * 128 + c02 + i) * MM + m;
            if (fl) ((float*)d_out)[off] = mx[i];
            else    ((unsigned short*)d_out)[off] = f2bf(mx[i]);
        }
    }
}

extern "C" void kernel_launch(void* const* d_in, const int* in_sizes, int n_in,
                              void* d_out, int out_size, void* d_ws, size_t ws_size,
                              hipStream_t stream) {
    (void)in_sizes; (void)n_in; (void)out_size; (void)ws_size;
    const void* feat = d_in[0];
    const void* coords = d_in[1];
    const void* temb = d_in[2];

    // compact workspace: ~1.9 MB total
    char* ws = (char*)d_ws;
    int* flag = (int*)ws;                                  // @0 (64 B reserved)
    float* coordsC = (float*)(ws + 64);                    // 393,216
    float* paramsC = (float*)(ws + 393280);                // 52,224
    float* centersF = (float*)(ws + 445504);               // 131,072
    int* nidx = (int*)(ws + 576576);                       // 1,048,576
    float* part1 = (float*)(ws + 1625152);                 // 131,072
    float* part2 = (float*)(ws + 1756224);                 // 131,072
    float* coef1 = (float*)(ws + 1887296);                 // 4,096
    float* coef2 = (float*)(ws + 1891392);                 // 8,192 -> ends 1,899,584

    k_detect<<<1, 64, 0, stream>>>((const unsigned short*)feat, flag);
    k_cvt<<<384, 256, 0, stream>>>(coords, coordsC, flag, BB * 3 * NN);
    k_cvt_params<<<51, 256, 0, stream>>>(d_in[3], d_in[4], d_in[5], d_in[6],
                                         d_in[7], d_in[8], d_in[9], d_in[10],
                                         paramsC, flag);
    k_fps<<<8, 256, 0, stream>>>(coordsC, centersF, d_out, flag);
    k_knn<<<8192, 64, 0, stream>>>(coordsC, centersF, nidx);
    k_gtemb<<<dim3(16, 8), 256, 0, stream>>>(temb, nidx, d_out, flag);
    k_mlp1s<<<2048, 256, 0, stream>>>(feat, coordsC, centersF, nidx, paramsC, part1, flag);
    k_coef1<<<1, 64, 0, stream>>>(part1, paramsC, coef1);
    k_mlp2s<<<2048, 256, 0, stream>>>(feat, coordsC, centersF, nidx, paramsC, coef1, part2, flag);
    k_coef2<<<1, 64, 0, stream>>>(part2, paramsC, coef2);
    k_final<<<2048, 256, 0, stream>>>(feat, coordsC, centersF, nidx, paramsC, coef1, coef2, d_out, flag);
}

// Round 7
// 1742.965 us; speedup vs baseline: 1.7510x; 1.1226x over previous
//
#include <hip/hip_runtime.h>
#include <stdint.h>

#define BB 8
#define NN 4096
#define MM 1024
#define KK 32

__device__ __forceinline__ float bf2f(unsigned short u) {
    union { unsigned int i; float f; } v; v.i = ((unsigned int)u) << 16; return v.f;
}
__device__ __forceinline__ unsigned short f2bf(float f) {
    union { float f; unsigned int i; } v; v.f = f;
    unsigned int x = v.i;
    x += 0x7fffu + ((x >> 16) & 1u);
    return (unsigned short)(x >> 16);
}
__device__ __forceinline__ float swishf(float y) {
    return __fdividef(y, 1.0f + __expf(-y));
}

// out element offsets (dtype-independent)
#define OUT1_OFF 1048576
#define OUT2_OFF 1073152

// params canonical f32 layout (floats)
#define P_W1 0
#define P_B1 4288
#define P_G1 4352
#define P_BE1 4416
#define P_W2 4480
#define P_B2 12672
#define P_G2 12800
#define P_BE2 12928

// ================= k_prep mega-kernel =================
// blocks 0..7: FPS (f64, one block per batch) | 8..519: featT transpose |
// 520..903: coords cvt | 904..954: params cvt.  All compute dtype flag
// locally from feat's first 128 ushorts (no separate detect kernel).
struct PW { double d; int p; int q; };
#define PSM_XS   ((float*)(PSM))
#define PSM_YS   ((float*)(PSM + 16384))
#define PSM_ZS   ((float*)(PSM + 32768))
#define PSM_HIST ((int*)(PSM + 49152))
#define PSM_PWB  ((PW*)(PSM + 53248))
#define PSM_SF   ((int*)(PSM + 53376))

__global__ __launch_bounds__(256) void k_prep(
    const void* __restrict__ feat, const void* __restrict__ coords,
    float* __restrict__ featT, float* __restrict__ coordsC,
    float* __restrict__ paramsC, float* __restrict__ centersF,
    void* __restrict__ d_out,
    const void* W1, const void* b1, const void* g1, const void* be1,
    const void* W2, const void* b2, const void* g2, const void* be2)
{
    __shared__ __align__(16) char PSM[53392];
    int tid = threadIdx.x;
    int blk = blockIdx.x;
    // local dtype detect (wave 0)
    if (tid < 64) {
        unsigned short u = ((const unsigned short*)feat)[tid * 2];
        float x = fabsf(bf2f(u));
        bool ext = (u != 0) && (x > 100.0f || x < 1e-30f);
        unsigned long long m = __ballot(ext);
        if (tid == 0) *PSM_SF = (__popcll(m) >= 16) ? 1 : 0;
    }
    __syncthreads();
    int fl = *PSM_SF;

    if (blk < 8) {
        // ---------- FPS in f64 (mirrors np float64 golden), 256 thr ----------
        int b = blk;
        if (fl) {
            const float* cb = (const float*)coords + (size_t)b * 3 * NN;
#pragma unroll
            for (int i = 0; i < 16; i++) {
                int p = tid + i * 256;
                PSM_XS[p] = cb[p]; PSM_YS[p] = cb[NN + p]; PSM_ZS[p] = cb[2 * NN + p];
            }
        } else {
            const unsigned short* cb = (const unsigned short*)coords + (size_t)b * 3 * NN;
#pragma unroll
            for (int i = 0; i < 16; i++) {
                int p = tid + i * 256;
                PSM_XS[p] = bf2f(cb[p]); PSM_YS[p] = bf2f(cb[NN + p]); PSM_ZS[p] = bf2f(cb[2 * NN + p]);
            }
        }
        if (tid == 0) PSM_HIST[0] = 0;
        __syncthreads();
        int base = tid * 16;
        double px[16], py[16], pz[16], dist[16];
        double x0 = (double)PSM_XS[0], y0 = (double)PSM_YS[0], z0 = (double)PSM_ZS[0];
        double bd = -1.0; int bp = base;
#pragma unroll
        for (int j = 0; j < 16; j++) {
            px[j] = (double)PSM_XS[base + j]; py[j] = (double)PSM_YS[base + j]; pz[j] = (double)PSM_ZS[base + j];
            double dx = px[j] - x0, dy = py[j] - y0, dz = pz[j] - z0;
            dist[j] = fma(dz, dz, fma(dy, dy, dx * dx));
            bool rep = dist[j] > bd;
            bd = rep ? dist[j] : bd; bp = rep ? base + j : bp;
        }
        int lane = tid & 63, wid = tid >> 6;
#pragma unroll 1
        for (int s = 1; s < MM; s++) {
#pragma unroll
            for (int m = 32; m >= 1; m >>= 1) {
                double od = __shfl_xor(bd, m, 64);
                int op = __shfl_xor(bp, m, 64);
                bool rep = (od > bd) || (od == bd && op < bp);
                bd = rep ? od : bd; bp = rep ? op : bp;
            }
            int par = s & 1;
            if (lane == 0) { PW w; w.d = bd; w.p = bp; w.q = 0; PSM_PWB[par * 4 + wid] = w; }
            __syncthreads();
            PW w0 = PSM_PWB[par * 4 + 0];
            double wd = w0.d; int wp = w0.p;
#pragma unroll
            for (int w = 1; w < 4; w++) {
                PW ww = PSM_PWB[par * 4 + w];
                bool rep = (ww.d > wd) || (ww.d == wd && ww.p < wp);
                wd = rep ? ww.d : wd; wp = rep ? ww.p : wp;
            }
            if (tid == 0) PSM_HIST[s] = wp;
            double fx = (double)PSM_XS[wp], fy = (double)PSM_YS[wp], fz = (double)PSM_ZS[wp];
            bd = -1.0; bp = base;
#pragma unroll
            for (int j = 0; j < 16; j++) {
                double dx = px[j] - fx, dy = py[j] - fy, dz = pz[j] - fz;
                double d = fma(dz, dz, fma(dy, dy, dx * dx));
                dist[j] = fmin(dist[j], d);
                bool rep = dist[j] > bd;
                bd = rep ? dist[j] : bd; bp = rep ? base + j : bp;
            }
        }
        __syncthreads();
#pragma unroll
        for (int i = 0; i < 4; i++) {
            int m = tid + i * 256;
            int far = PSM_HIST[m];
            float X = PSM_XS[far], Y = PSM_YS[far], Z = PSM_ZS[far];
            if (fl) {
                float* o = (float*)d_out;
                o[OUT1_OFF + (size_t)(b * 3 + 0) * MM + m] = X;
                o[OUT1_OFF + (size_t)(b * 3 + 1) * MM + m] = Y;
                o[OUT1_OFF + (size_t)(b * 3 + 2) * MM + m] = Z;
            } else {
                unsigned short* o = (unsigned short*)d_out;
                o[OUT1_OFF + (size_t)(b * 3 + 0) * MM + m] = f2bf(X);
                o[OUT1_OFF + (size_t)(b * 3 + 1) * MM + m] = f2bf(Y);
                o[OUT1_OFF + (size_t)(b * 3 + 2) * MM + m] = f2bf(Z);
            }
            *(float4*)(centersF + ((size_t)b * MM + m) * 4) = make_float4(X, Y, Z, 0.f);
        }
    } else if (blk < 520) {
        // ---------- featT: [B,64,N] -> f32 [B,N,64] ----------
        int i = blk - 8;
        int b = i >> 6, n0 = (i & 63) * 64;
        float (*tile)[65] = (float(*)[65])PSM;
        int c = tid >> 2, q = tid & 3;
        size_t base = ((size_t)b * 64 + c) * NN + n0 + q * 16;
        if (fl) {
            const float* sp = (const float*)feat + base;
#pragma unroll
            for (int j = 0; j < 16; j++) tile[c][q * 16 + j] = sp[j];
        } else {
            const unsigned short* sp = (const unsigned short*)feat + base;
#pragma unroll
            for (int j = 0; j < 16; j++) tile[c][q * 16 + j] = bf2f(sp[j]);
        }
        __syncthreads();
        int n = tid >> 2;
        float* dp = featT + ((size_t)b * NN + n0 + n) * 64 + q * 16;
#pragma unroll
        for (int j = 0; j < 16; j++) dp[j] = tile[q * 16 + j][n];
    } else if (blk < 904) {
        // ---------- coords -> coordsC f32 ----------
        int idx = (blk - 520) * 256 + tid;
        coordsC[idx] = fl ? ((const float*)coords)[idx]
                          : bf2f(((const unsigned short*)coords)[idx]);
    } else {
        // ---------- params -> paramsC f32 ----------
        int idx = (blk - 904) * 256 + tid;
        if (idx < 13056) {
            const void* src; int off;
            if (idx < 4288)       { src = W1;  off = idx; }
            else if (idx < 4352)  { src = b1;  off = idx - 4288; }
            else if (idx < 4416)  { src = g1;  off = idx - 4352; }
            else if (idx < 4480)  { src = be1; off = idx - 4416; }
            else if (idx < 12672) { src = W2;  off = idx - 4480; }
            else if (idx < 12800) { src = b2;  off = idx - 12672; }
            else if (idx < 12928) { src = g2;  off = idx - 12800; }
            else                  { src = be2; off = idx - 12928; }
            paramsC[idx] = fl ? ((const float*)src)[off]
                              : bf2f(((const unsigned short*)src)[off]);
        }
    }
}

// ================= kNN (f64, K=32 lex) + fused gtemb-max =================
#define RESCAN(G) { \
    double gd = 1.0e300; int ga = (G) * 8; \
    _Pragma("unroll") \
    for (int i = 0; i < 8; i++) { \
        int sl = (G) * 8 + i; \
        unsigned int bit = (sl < 32) ? (elo >> sl) : (ehi >> (sl - 32)); \
        double cd = (bit & 1u) ? 1.0e300 : d[sl]; \
        bool rep = cd < gd; \
        gd = rep ? cd : gd; ga = rep ? sl : ga; \
    } \
    g8[(G)] = gd; a8[(G)] = ga; }

__global__ __launch_bounds__(64, 1) void k_knn(
    const float* __restrict__ coordsC,
    const float* __restrict__ centersF,
    int* __restrict__ nidx,
    const void* __restrict__ temb,
    const void* __restrict__ feat,
    void* __restrict__ d_out)
{
    int bm = blockIdx.x;
    int b = bm >> 10;
    int lane = threadIdx.x;
    // local dtype detect (single wave)
    unsigned short du = ((const unsigned short*)feat)[lane * 2];
    float dx0 = fabsf(bf2f(du));
    bool ext = (du != 0) && (dx0 > 100.0f || dx0 < 1e-30f);
    unsigned long long dm = __ballot(ext);
    int fl = (__popcll(dm) >= 16) ? 1 : 0;

    const float* cb = coordsC + (size_t)b * 3 * NN;
    float4 ctr = *(const float4*)(centersF + (size_t)bm * 4);
    double cx = (double)ctr.x, cy = (double)ctr.y, cz = (double)ctr.z;
    double cc = (cx * cx + cy * cy) + cz * cz;
    double d[64];
#pragma unroll 4
    for (int j = 0; j < 64; j++) {
        int p = j * 64 + lane;
        double x = (double)cb[p], y = (double)cb[NN + p], z = (double)cb[2 * NN + p];
        double pp = (x * x + y * y) + z * z;
        double dt = (cx * x + cy * y) + cz * z;
        d[j] = (cc + pp) - 2.0 * dt;
    }
    double g8[8]; int a8[8];
#pragma unroll
    for (int g = 0; g < 8; g++) {
        double gd = d[g * 8]; int ga = g * 8;
#pragma unroll
        for (int i = 1; i < 8; i++) {
            int sl = g * 8 + i;
            bool rep = d[sl] < gd;
            gd = rep ? d[sl] : gd; ga = rep ? sl : ga;
        }
        g8[g] = gd; a8[g] = ga;
    }
    unsigned int elo = 0, ehi = 0;
    int res = 0;
#pragma unroll 1
    for (int it = 0; it < 32; it++) {
        double bd = g8[0]; int ba = a8[0];
#pragma unroll
        for (int g = 1; g < 8; g++) {
            bool rep = g8[g] < bd;
            bd = rep ? g8[g] : bd; ba = rep ? a8[g] : ba;
        }
        int bp = ba * 64 + lane;
        double wd = bd; int wp = bp;
#pragma unroll
        for (int s = 32; s >= 1; s >>= 1) {
            double od = __shfl_xor(wd, s, 64);
            int op = __shfl_xor(wp, s, 64);
            bool rep = (od < wd) || (od == wd && op < wp);
            wd = rep ? od : wd; wp = rep ? op : wp;
        }
        res = (lane == it) ? wp : res;
        if (bp == wp) {
            int slot = ba;
            if (slot < 32) elo |= (1u << slot); else ehi |= (1u << (slot - 32));
            int g = slot >> 3;
            switch (g) {
                case 0: RESCAN(0) break;
                case 1: RESCAN(1) break;
                case 2: RESCAN(2) break;
                case 3: RESCAN(3) break;
                case 4: RESCAN(4) break;
                case 5: RESCAN(5) break;
                case 6: RESCAN(6) break;
                case 7: RESCAN(7) break;
            }
        }
    }
    if (lane < KK) nidx[(size_t)bm * KK + lane] = res;
    // ---- fused gtemb: channel = lane, neighbors broadcast via shuffle ----
    int m = bm & (MM - 1);
    float best = -3.0e38f;
    if (fl) {
        const float* tb = (const float*)temb + ((size_t)b * 64 + lane) * NN;
#pragma unroll 4
        for (int k = 0; k < 32; k++) {
            int nk = __shfl(res, k, 64);
            best = fmaxf(best, tb[nk]);
        }
    } else {
        const unsigned short* tb = (const unsigned short*)temb + ((size_t)b * 64 + lane) * NN;
#pragma unroll 4
        for (int k = 0; k < 32; k++) {
            int nk = __shfl(res, k, 64);
            best = fmaxf(best, bf2f(tb[nk]));
        }
    }
    size_t off = (size_t)OUT2_OFF + ((size_t)(b * 64 + lane)) * MM + m;
    if (fl) ((float*)d_out)[off] = best;
    else    ((unsigned short*)d_out)[off] = f2bf(best);
}

// ================= fused MLP machinery (featT f32 gathers) =================
// phase1 LDS: w1t[67][64] @0 (17152) | gbuf[4][32][66] @17152 (33792)
//   | gc[4][3][32] @50944 (1536) | nid[4][32] @52480 (512) | sred @52992 (256)
// phase2 LDS (after barrier, overlaps): w2t[64][128] @0 (32768) |
//   act[4][64][32] @32768 (32768) -> 65536
#define W1Tm(j,c)     (((float*)SM)[(j)*64+(c)])
#define GBUFm(mi,k,c) (((float*)(SM+17152))[(((mi)*32+(k))*66)+(c)])
#define GCm(mi,j,k)   (((float*)(SM+50944))[(((mi)*3+(j))*32)+(k)])
#define NDm(mi,k)     (((int*)(SM+52480))[((mi)*32)+(k)])
#define W2Tm(j,c)     (((float*)SM)[(j)*128+(c)])
#define ACTm(mi,j,k)  (((float*)(SM+32768))[(((mi)*64+(j))*32)+(k)])

__device__ __forceinline__ void mlp1_compute(
    char* SM, int tid, int lane, int mi, int b, int bm,
    const float* __restrict__ featT, const float* __restrict__ coordsC,
    const float* __restrict__ centersF, const int* __restrict__ nidx,
    const float* __restrict__ P, float acc[8][4])
{
    for (int t = tid; t < 64 * 67; t += 256) {
        int c = t / 67, j = t % 67;
        W1Tm(j, c) = P[P_W1 + t];
    }
    if (lane < 32) NDm(mi, lane) = nidx[(size_t)bm * KK + lane] & (NN - 1);
    __syncthreads();
    const float* fb = featT + (size_t)b * NN * 64;
#pragma unroll 4
    for (int q = 0; q < 32; q++) {
        int n = NDm(mi, q);
        GBUFm(mi, q, lane) = fb[(size_t)n * 64 + lane];
    }
    float4 ctr = *(const float4*)(centersF + (size_t)bm * 4);
    const float* cb = coordsC + (size_t)b * 3 * NN;
    if (lane < 32) {
        int n = NDm(mi, lane);
        GCm(mi, 0, lane) = __fsub_rn(cb[n], ctr.x);
        GCm(mi, 1, lane) = __fsub_rn(cb[NN + n], ctr.y);
        GCm(mi, 2, lane) = __fsub_rn(cb[2 * NN + n], ctr.z);
    }
    __syncthreads();
    int c0 = (lane >> 3) * 8;
    int k0 = (lane & 7) * 4;
#pragma unroll
    for (int i = 0; i < 8; i++)
#pragma unroll
        for (int kk = 0; kk < 4; kk++) acc[i][kk] = 0.f;
#pragma unroll
    for (int j = 0; j < 3; j++) {
        float4 a = *(const float4*)&GCm(mi, j, k0);
        float4 w0 = *(const float4*)&W1Tm(j, c0);
        float4 w1v = *(const float4*)&W1Tm(j, c0 + 4);
        float w[8] = {w0.x, w0.y, w0.z, w0.w, w1v.x, w1v.y, w1v.z, w1v.w};
#pragma unroll
        for (int i = 0; i < 8; i++) {
            acc[i][0] = fmaf(w[i], a.x, acc[i][0]);
            acc[i][1] = fmaf(w[i], a.y, acc[i][1]);
            acc[i][2] = fmaf(w[i], a.z, acc[i][2]);
            acc[i][3] = fmaf(w[i], a.w, acc[i][3]);
        }
    }
#pragma unroll 4
    for (int c = 0; c < 64; c++) {
        float f0 = GBUFm(mi, k0 + 0, c);
        float f1 = GBUFm(mi, k0 + 1, c);
        float f2 = GBUFm(mi, k0 + 2, c);
        float f3 = GBUFm(mi, k0 + 3, c);
        int j = 3 + c;
        float4 w0 = *(const float4*)&W1Tm(j, c0);
        float4 w1v = *(const float4*)&W1Tm(j, c0 + 4);
        float w[8] = {w0.x, w0.y, w0.z, w0.w, w1v.x, w1v.y, w1v.z, w1v.w};
#pragma unroll
        for (int i = 0; i < 8; i++) {
            acc[i][0] = fmaf(w[i], f0, acc[i][0]);
            acc[i][1] = fmaf(w[i], f1, acc[i][1]);
            acc[i][2] = fmaf(w[i], f2, acc[i][2]);
            acc[i][3] = fmaf(w[i], f3, acc[i][3]);
        }
    }
}

__device__ __forceinline__ void mlp2_compute(
    char* SM, int tid, int lane, int mi, int b,
    const float acc1[8][4], const float* __restrict__ coef1,
    const float* __restrict__ P, float acc2[16][4])
{
    __syncthreads();  // phase1 LDS dead
    int c0 = (lane >> 3) * 8;
    int k0 = (lane & 7) * 4;
#pragma unroll
    for (int i = 0; i < 8; i++) {
        int c = c0 + i;
        float sc = coef1[(b * 64 + c) * 2];
        float sh = coef1[(b * 64 + c) * 2 + 1];
        float bb = P[P_B1 + c];
#pragma unroll
        for (int kk = 0; kk < 4; kk++)
            ACTm(mi, c, k0 + kk) = swishf(fmaf(acc1[i][kk] + bb, sc, sh));
    }
    for (int t = tid; t < 128 * 64; t += 256) {
        int c = t >> 6, j = t & 63;
        W2Tm(j, c) = P[P_W2 + t];
    }
    __syncthreads();
    int c02 = (lane >> 3) * 16;
#pragma unroll
    for (int i = 0; i < 16; i++)
#pragma unroll
        for (int kk = 0; kk < 4; kk++) acc2[i][kk] = 0.f;
#pragma unroll 4
    for (int j = 0; j < 64; j++) {
        float4 a = *(const float4*)&ACTm(mi, j, k0);
        float4 w0 = *(const float4*)&W2Tm(j, c02);
        float4 w1v = *(const float4*)&W2Tm(j, c02 + 4);
        float4 w2v = *(const float4*)&W2Tm(j, c02 + 8);
        float4 w3 = *(const float4*)&W2Tm(j, c02 + 12);
        float w[16] = {w0.x, w0.y, w0.z, w0.w, w1v.x, w1v.y, w1v.z, w1v.w,
                       w2v.x, w2v.y, w2v.z, w2v.w, w3.x, w3.y, w3.z, w3.w};
#pragma unroll
        for (int i = 0; i < 16; i++) {
            acc2[i][0] = fmaf(w[i], a.x, acc2[i][0]);
            acc2[i][1] = fmaf(w[i], a.y, acc2[i][1]);
            acc2[i][2] = fmaf(w[i], a.z, acc2[i][2]);
            acc2[i][3] = fmaf(w[i], a.w, acc2[i][3]);
        }
    }
}

// ---------------- MLP1 + GN1 block-partial stats
__global__ __launch_bounds__(256) void k_mlp1s(
    const float* __restrict__ featT, const float* __restrict__ coordsC,
    const float* __restrict__ centersF, const int* __restrict__ nidx,
    const float* __restrict__ P, float* __restrict__ part1)
{
    __shared__ __align__(16) char smem[53248];
    char* SM = smem;
    int tid = threadIdx.x, blk = blockIdx.x;
    int b = blk >> 8, m0 = (blk & 255) * 4;
    int mi = tid >> 6, lane = tid & 63;
    int bm = b * MM + m0 + mi;
    float acc[8][4];
    mlp1_compute(SM, tid, lane, mi, b, bm, featT, coordsC, centersF, nidx, P, acc);
    int c0 = (lane >> 3) * 8;
    float s = 0.f, s2 = 0.f;
#pragma unroll
    for (int i = 0; i < 8; i++) {
        float bb = P[P_B1 + c0 + i];
#pragma unroll
        for (int kk = 0; kk < 4; kk++) {
            float v = acc[i][kk] + bb;
            s += v; s2 = fmaf(v, v, s2);
        }
    }
    s += __shfl_xor(s, 1, 64); s += __shfl_xor(s, 2, 64); s += __shfl_xor(s, 4, 64);
    s2 += __shfl_xor(s2, 1, 64); s2 += __shfl_xor(s2, 2, 64); s2 += __shfl_xor(s2, 4, 64);
    float* sred = (float*)(SM + 52992);
    __syncthreads();
    if ((lane & 7) == 0) {
        int g = lane >> 3;
        sred[(mi * 8 + g) * 2] = s;
        sred[(mi * 8 + g) * 2 + 1] = s2;
    }
    __syncthreads();
    if (tid < 16) {
        int g = tid >> 1, w = tid & 1;
        float t = sred[(0 * 8 + g) * 2 + w] + sred[(1 * 8 + g) * 2 + w]
                + sred[(2 * 8 + g) * 2 + w] + sred[(3 * 8 + g) * 2 + w];
        part1[blk * 16 + g * 2 + w] = t;
    }
}

// ---------------- parallel coef reductions (512 thr, tree)
__global__ __launch_bounds__(512) void k_coef1(
    const float* __restrict__ part1, const float* __restrict__ P,
    float* __restrict__ coef1)
{
    __shared__ float red[512];
    int tid = threadIdx.x;
    int out = tid >> 2, sub = tid & 3;   // out = b*16 + g*2 + w
    int b = out >> 4, gw = out & 15;
    const float* p = part1 + (size_t)(b * 256 + sub * 64) * 16 + gw;
    float s = 0.f;
#pragma unroll 8
    for (int r = 0; r < 64; r++) s += p[r * 16];
    red[out * 4 + sub] = s;
    __syncthreads();
    if (tid < 64) {
        int bb = tid >> 3, g = tid & 7;
        int o1 = (bb * 16 + g * 2) * 4, o2 = o1 + 4;
        float S = red[o1] + red[o1 + 1] + red[o1 + 2] + red[o1 + 3];
        float Q = red[o2] + red[o2 + 1] + red[o2 + 2] + red[o2 + 3];
        float inv_n = 1.0f / 262144.0f;
        float mean = S * inv_n;
        float var = Q * inv_n - mean * mean;
        float inv = rsqrtf(var + 1e-5f);
        for (int i = 0; i < 8; i++) {
            int c = g * 8 + i;
            float sc = P[P_G1 + c] * inv;
            coef1[(bb * 64 + c) * 2] = sc;
            coef1[(bb * 64 + c) * 2 + 1] = P[P_BE1 + c] - mean * sc;
        }
    }
}

// ---------------- MLP1+act+MLP2 + GN2 block-partial stats
__global__ __launch_bounds__(256) void k_mlp2s(
    const float* __restrict__ featT, const float* __restrict__ coordsC,
    const float* __restrict__ centersF, const int* __restrict__ nidx,
    const float* __restrict__ P, const float* __restrict__ coef1,
    float* __restrict__ part2)
{
    __shared__ __align__(16) char smem[65536];
    char* SM = smem;
    int tid = threadIdx.x, blk = blockIdx.x;
    int b = blk >> 8, m0 = (blk & 255) * 4;
    int mi = tid >> 6, lane = tid & 63;
    int bm = b * MM + m0 + mi;
    float acc1[8][4];
    mlp1_compute(SM, tid, lane, mi, b, bm, featT, coordsC, centersF, nidx, P, acc1);
    float acc2[16][4];
    mlp2_compute(SM, tid, lane, mi, b, acc1, coef1, P, acc2);
    int c02 = (lane >> 3) * 16;
    float s = 0.f, s2 = 0.f;
#pragma unroll
    for (int i = 0; i < 16; i++) {
        float bb = P[P_B2 + c02 + i];
#pragma unroll
        for (int kk = 0; kk < 4; kk++) {
            float v = acc2[i][kk] + bb;
            s += v; s2 = fmaf(v, v, s2);
        }
    }
    s += __shfl_xor(s, 1, 64); s += __shfl_xor(s, 2, 64); s += __shfl_xor(s, 4, 64);
    s2 += __shfl_xor(s2, 1, 64); s2 += __shfl_xor(s2, 2, 64); s2 += __shfl_xor(s2, 4, 64);
    __syncthreads();  // phase2 LDS dead
    float* sred = (float*)SM;
    if ((lane & 7) == 0) {
        int g = lane >> 3;
        sred[(mi * 8 + g) * 2] = s;
        sred[(mi * 8 + g) * 2 + 1] = s2;
    }
    __syncthreads();
    if (tid < 16) {
        int g = tid >> 1, w = tid & 1;
        float t = sred[(0 * 8 + g) * 2 + w] + sred[(1 * 8 + g) * 2 + w]
                + sred[(2 * 8 + g) * 2 + w] + sred[(3 * 8 + g) * 2 + w];
        part2[blk * 16 + g * 2 + w] = t;
    }
}

__global__ __launch_bounds__(512) void k_coef2(
    const float* __restrict__ part2, const float* __restrict__ P,
    float* __restrict__ coef2)
{
    __shared__ float red[512];
    int tid = threadIdx.x;
    int out = tid >> 2, sub = tid & 3;
    int b = out >> 4, gw = out & 15;
    const float* p = part2 + (size_t)(b * 256 + sub * 64) * 16 + gw;
    float s = 0.f;
#pragma unroll 8
    for (int r = 0; r < 64; r++) s += p[r * 16];
    red[out * 4 + sub] = s;
    __syncthreads();
    if (tid < 64) {
        int bb = tid >> 3, g = tid & 7;
        int o1 = (bb * 16 + g * 2) * 4, o2 = o1 + 4;
        float S = red[o1] + red[o1 + 1] + red[o1 + 2] + red[o1 + 3];
        float Q = red[o2] + red[o2 + 1] + red[o2 + 2] + red[o2 + 3];
        float inv_n = 1.0f / 524288.0f;
        float mean = S * inv_n;
        float var = Q * inv_n - mean * mean;
        float inv = rsqrtf(var + 1e-5f);
        for (int i = 0; i < 16; i++) {
            int c = g * 16 + i;
            float sc = P[P_G2 + c] * inv;
            coef2[(bb * 128 + c) * 2] = sc;
            coef2[(bb * 128 + c) * 2 + 1] = P[P_BE2 + c] - mean * sc;
        }
    }
}

// ---------------- final: recompute, swish(GN2), max over K -> out0
__global__ __launch_bounds__(256) void k_final(
    const float* __restrict__ featT, const float* __restrict__ coordsC,
    const float* __restrict__ centersF, const int* __restrict__ nidx,
    const float* __restrict__ P, const float* __restrict__ coef1,
    const float* __restrict__ coef2,
    void* __restrict__ d_out, const void* __restrict__ feat)
{
    __shared__ __align__(16) char smem[65536];
    char* SM = smem;
    int tid = threadIdx.x, blk = blockIdx.x;
    // local dtype detect for output encoding (LDS slot past phase1 region)
    if (tid < 64) {
        unsigned short u = ((const unsigned short*)feat)[tid * 2];
        float x = fabsf(bf2f(u));
        bool ext = (u != 0) && (x > 100.0f || x < 1e-30f);
        unsigned long long m = __ballot(ext);
        if (tid == 0) *(int*)(SM + 53248) = (__popcll(m) >= 16) ? 1 : 0;
    }
    __syncthreads();
    int fl = *(int*)(SM + 53248);
    int b = blk >> 8, m0 = (blk & 255) * 4;
    int mi = tid >> 6, lane = tid & 63;
    int bm = b * MM + m0 + mi;
    float acc1[8][4];
    mlp1_compute(SM, tid, lane, mi, b, bm, featT, coordsC, centersF, nidx, P, acc1);
    float acc2[16][4];
    mlp2_compute(SM, tid, lane, mi, b, acc1, coef1, P, acc2);
    int c02 = (lane >> 3) * 16;
    float mx[16];
#pragma unroll
    for (int i = 0; i < 16; i++) {
        int c = c02 + i;
        float sc = coef2[(b * 128 + c) * 2];
        float sh = coef2[(b * 128 + c) * 2 + 1];
        float bb = P[P_B2 + c];
        float v = -3.0e38f;
#pragma unroll
        for (int kk = 0; kk < 4; kk++)
            v = fmaxf(v, swishf(fmaf(acc2[i][kk] + bb, sc, sh)));
        v = fmaxf(v, __shfl_xor(v, 1, 64));
        v = fmaxf(v, __shfl_xor(v, 2, 64));
        v = fmaxf(v, __shfl_xor(v, 4, 64));
        mx[i] = v;
    }
    if ((lane & 7) == 0) {
        int m = m0 + mi;
#pragma unroll
        for (int i = 0; i < 16; i++) {
            size_t off = (size_t)(b * 128 + c02 + i) * MM + m;
            if (fl) ((float*)d_out)[off] = mx[i];
            else    ((unsigned short*)d_out)[off] = f2bf(mx[i]);
        }
    }
}

extern "C" void kernel_launch(void* const* d_in, const int* in_sizes, int n_in,
                              void* d_out, int out_size, void* d_ws, size_t ws_size,
                              hipStream_t stream) {
    (void)in_sizes; (void)n_in; (void)out_size; (void)ws_size;
    const void* feat = d_in[0];
    const void* coords = d_in[1];
    const void* temb = d_in[2];

    // workspace: 10,288,192 bytes total (== round-3 proven size)
    char* ws = (char*)d_ws;
    float* coordsC = (float*)(ws + 64);                    // 393,216
    float* paramsC = (float*)(ws + 393280);                // 52,224
    float* centersF = (float*)(ws + 445504);               // 131,072
    int* nidx = (int*)(ws + 576576);                       // 1,048,576
    float* part1 = (float*)(ws + 1625152);                 // 131,072
    float* part2 = (float*)(ws + 1756224);                 // 131,072
    float* coef1 = (float*)(ws + 1887296);                 // 4,096
    float* coef2 = (float*)(ws + 1891392);                 // 8,192
    float* featT = (float*)(ws + 1899584);                 // 8,388,608 -> ends 10,288,192

    k_prep<<<955, 256, 0, stream>>>(feat, coords, featT, coordsC, paramsC,
                                    centersF, d_out,
                                    d_in[3], d_in[4], d_in[5], d_in[6],
                                    d_in[7], d_in[8], d_in[9], d_in[10]);
    k_knn<<<8192, 64, 0, stream>>>(coordsC, centersF, nidx, temb, feat, d_out);
    k_mlp1s<<<2048, 256, 0, stream>>>(featT, coordsC, centersF, nidx, paramsC, part1);
    k_coef1<<<1, 512, 0, stream>>>(part1, paramsC, coef1);
    k_mlp2s<<<2048, 256, 0, stream>>>(featT, coordsC, centersF, nidx, paramsC, coef1, part2);
    k_coef2<<<1, 512, 0, stream>>>(part2, paramsC, coef2);
    k_final<<<2048, 256, 0, stream>>>(featT, coordsC, centersF, nidx, paramsC, coef1, coef2, d_out, feat);
}